// Round 19
// baseline (177.451 us; speedup 1.0000x reference)
//
#include <hip/hip_runtime.h>
#include <stdint.h>

typedef __attribute__((ext_vector_type(8))) short short8;
typedef __attribute__((ext_vector_type(4))) float f32x4;

static __device__ __forceinline__ ushort f2bf(float f) {
  uint32_t u = __float_as_uint(f);
  uint32_t r = (u + 0x7FFFu + ((u >> 16) & 1u)) >> 16;
  return (ushort)r;
}
static __device__ __forceinline__ float bf2f(ushort h) {
  return __uint_as_float(((uint32_t)h) << 16);
}

// Branchless top-3 insert, f64 (used only in the 4-candidate refine).
static __device__ __forceinline__ void ins3b(double d, int i,
    double& b0, double& b1, double& b2, int& i0, int& i1, int& i2) {
  const bool c0 = d < b0, c1 = d < b1, c2 = d < b2;
  const double nb0 = c0 ? d : b0;
  const int    ni0 = c0 ? i : i0;
  const double nb1 = c0 ? b0 : (c1 ? d : b1);
  const int    ni1 = c0 ? i0 : (c1 ? i : i1);
  const double nb2 = c1 ? b1 : (c2 ? d : b2);
  const int    ni2 = c1 ? i1 : (c2 ? i : i2);
  b0 = nb0; b1 = nb1; b2 = nb2; i0 = ni0; i1 = ni1; i2 = ni2;
}

// ---------------------------------------------------------------------------
// prep: blocks 0..255 = KNN (point-per-lane, candidate-BROADCAST scan:
//       all 64 lanes read the same pc4[j] -> LDS broadcast, no merge needed;
//       packed-key u32 top-4 + per-lane f64 refine — selection identical to
//       the split-scan version since keys are globally distinct);
//       256..2303 = x f32->bf16; 2304..6399 = x_skip f32->bf16;
//       6400..8959 = weight converts.
// ---------------------------------------------------------------------------
__global__ __launch_bounds__(256) void prep_kernel(
    const float* __restrict__ pos, const float* __restrict__ pos_skip,
    const float* __restrict__ x, const float* __restrict__ xs,
    const float* __restrict__ W1, const float* __restrict__ W2,
    int4* __restrict__ idx_out, float4* __restrict__ w_out,
    ushort* __restrict__ xbf, ushort* __restrict__ xsbf,
    ushort* __restrict__ W1at, ushort* __restrict__ W1bt,
    ushort* __restrict__ W2t)
{
  __shared__ float pc4[4096];          // [1024][4] padded coarse positions
  if (blockIdx.x < 256) {
    const int b   = blockIdx.x >> 4;      // 16 blocks per batch
    const int blk = blockIdx.x & 15;      // 256 points per block
    for (int i = threadIdx.x; i < 1024; i += 256) {
      const float* ps = pos + (size_t)b * 3072 + i * 3;
      float4 v = { ps[0], ps[1], ps[2], 0.f };
      *(float4*)&pc4[i * 4] = v;
    }
    __syncthreads();

    const int row = b * 4096 + blk * 256 + threadIdx.x;
    const float pxf = pos_skip[(size_t)row * 3 + 0];
    const float pyf = pos_skip[(size_t)row * 3 + 1];
    const float pzf = pos_skip[(size_t)row * 3 + 2];

    uint32_t c0 = 0xFFFFFFFFu, c1 = 0xFFFFFFFFu, c2 = 0xFFFFFFFFu, c3 = 0xFFFFFFFFu;
    auto ins4u = [&](uint32_t k) {
      const bool l0 = k < c0, l1 = k < c1, l2 = k < c2, l3 = k < c3;
      const uint32_t n0 = l0 ? k  : c0;
      const uint32_t n1 = l0 ? c0 : (l1 ? k : c1);
      const uint32_t n2 = l1 ? c1 : (l2 ? k : c2);
      const uint32_t n3 = l2 ? c2 : (l3 ? k : c3);
      c0 = n0; c1 = n1; c2 = n2; c3 = n3;
    };
    // candidate-broadcast scan: every lane reads the SAME pc4[j] (free
    // LDS broadcast); each lane tracks top-4 for its own point.
#pragma unroll 4
    for (int j = 0; j < 1024; ++j) {
      const float4 q = *(const float4*)&pc4[j * 4];
      const float dx = q.x - pxf;
      const float dy = q.y - pyf;
      const float dz = q.z - pzf;
      const float d = fmaf(dx, dx, fmaf(dy, dy, dz * dz));
      ins4u((__float_as_uint(d) & 0xFFFFFC00u) | (uint32_t)j);
    }
    // per-lane f64 refine of the 4 survivors (exact selection + weights)
    {
      const double pxd = (double)pxf, pyd = (double)pyf, pzd = (double)pzf;
      auto exd = [&](int i) -> double {
        const double dx = (double)pc4[i * 4 + 0] - pxd;
        const double dy = (double)pc4[i * 4 + 1] - pyd;
        const double dz = (double)pc4[i * 4 + 2] - pzd;
        return dx * dx + dy * dy + dz * dz;
      };
      const int j0 = (int)(c0 & 1023u), j1 = (int)(c1 & 1023u);
      const int j2 = (int)(c2 & 1023u), j3 = (int)(c3 & 1023u);
      double b0 = 1e300, b1 = 1e300, b2 = 1e300;
      int i0 = 0, i1 = 0, i2 = 0;
      ins3b(exd(j0), j0, b0, b1, b2, i0, i1, i2);
      ins3b(exd(j1), j1, b0, b1, b2, i0, i1, i2);
      ins3b(exd(j2), j2, b0, b1, b2, i0, i1, i2);
      ins3b(exd(j3), j3, b0, b1, b2, i0, i1, i2);
      const double w0 = 1.0 / (sqrt(b0) + 1e-8);
      const double w1 = 1.0 / (sqrt(b1) + 1e-8);
      const double w2 = 1.0 / (sqrt(b2) + 1e-8);
      const double den = w0 + w1 + w2 + 1e-8;
      idx_out[row] = make_int4(i0, i1, i2, 0);
      w_out[row] = make_float4((float)(w0 / den), (float)(w1 / den), (float)(w2 / den), 0.f);
    }
  } else if (blockIdx.x < 2304) {
    const int id = (blockIdx.x - 256) * 256 + threadIdx.x;    // x: 2,097,152 f4
#pragma unroll
    for (int it = 0; it < 4; ++it) {
      const int i = id + it * 524288;
      const float4 v = *(const float4*)(x + (size_t)i * 4);
      ushort4 o = { f2bf(v.x), f2bf(v.y), f2bf(v.z), f2bf(v.w) };
      *(ushort4*)(xbf + (size_t)i * 4) = o;
    }
  } else if (blockIdx.x < 6400) {
    const int id = (blockIdx.x - 2304) * 256 + threadIdx.x;   // xs: 4,194,304 f4
#pragma unroll
    for (int it = 0; it < 4; ++it) {
      const int i = id + it * 1048576;
      const float4 v = *(const float4*)(xs + (size_t)i * 4);
      ushort4 o = { f2bf(v.x), f2bf(v.y), f2bf(v.z), f2bf(v.w) };
      *(ushort4*)(xsbf + (size_t)i * 4) = o;
    }
  } else {
    const int id = (blockIdx.x - 6400) * 256 + threadIdx.x;
    if (id < 262144) {                       // W1at[n][k] = W1[k][n], k<512
      const int n = id >> 9, k = id & 511;
      W1at[id] = f2bf(W1[(size_t)k * 512 + n]);
    } else if (id < 393216) {                // W1bt[n][k] = W1[512+k][n], k<256
      const int id2 = id - 262144;
      const int n = id2 >> 8, k = id2 & 255;
      W1bt[id2] = f2bf(W1[(size_t)(512 + k) * 512 + n]);
    } else if (id < 655360) {                // W2t[n][k] = W2[k][n]
      const int id3 = id - 393216;
      const int n = id3 >> 9, k = id3 & 511;
      W2t[id3] = f2bf(W2[(size_t)k * 512 + n]);
    }
  }
}

// ---------------------------------------------------------------------------
// 256x256 8-phase bf16 MFMA GEMM (T1..T5).
// COMBINE epilogue (S-GEMM): h2 = relu(acc + gather3(Y) + b1) -> bf16,
// eliminating the S round trip entirely. acc is the f32 x_skip@W1b partial.
// ---------------------------------------------------------------------------
template<int K, bool OUT_BF16, bool ACT, bool COMBINE>
__global__ __launch_bounds__(512, 2) void gemm_bias_relu(
    const ushort* __restrict__ A, const ushort* __restrict__ Bt,
    const float* __restrict__ bias, void* __restrict__ Cout, int M, int N,
    const ushort* __restrict__ Ybf, const int4* __restrict__ idx3,
    const float4* __restrict__ w3)
{
  constexpr int BM = 256, BN = 256, BK = 64, NT = K / BK;
  __shared__ ushort Asm[2][BM * BK];   // 2 x 32 KB
  __shared__ ushort Bsm[2][BN * BK];   // 2 x 32 KB
  const int tid  = threadIdx.x;
  const int lane = tid & 63;
  const int wave = tid >> 6;

  const int cpx  = gridDim.x >> 3;
  const int wgid = (blockIdx.x & 7) * cpx + (blockIdx.x >> 3);
  const int nbn  = N / BN;
  const int bm   = wgid / nbn;
  const int bn   = wgid - bm * nbn;
  const int row0 = bm * BM, col0 = bn * BN;
  const int wr = wave >> 2, wc = wave & 3;
  const int sbase = wave * 4096 + lane * 16;

  f32x4 acc[8][4] = {};

  auto stageA = [&](int buf, int kt) {
#pragma unroll
    for (int i = 0; i < 4; ++i) {
      const int o = sbase + i * 1024;
      const int r = o >> 7, s = (o & 127) >> 4;
      __builtin_amdgcn_global_load_lds(
          (const __attribute__((address_space(1))) void*)(A + (size_t)(row0 + r) * K + kt * BK + ((s ^ (r & 7)) << 3)),
          (__attribute__((address_space(3))) void*)((char*)&Asm[buf][0] + o), 16, 0, 0);
    }
  };
  auto stageB = [&](int buf, int kt) {
#pragma unroll
    for (int i = 0; i < 4; ++i) {
      const int o = sbase + i * 1024;
      const int r = o >> 7, s = (o & 127) >> 4;
      __builtin_amdgcn_global_load_lds(
          (const __attribute__((address_space(1))) void*)(Bt + (size_t)(col0 + r) * K + kt * BK + ((s ^ (r & 7)) << 3)),
          (__attribute__((address_space(3))) void*)((char*)&Bsm[buf][0] + o), 16, 0, 0);
    }
  };
  auto rdA = [&](int buf, int mi, int kk) -> short8 {
    const int ra = wr * 128 + mi * 16 + (lane & 15);
    const int s  = kk * 4 + (lane >> 4);
    return *(const short8*)((const char*)&Asm[buf][0] + ra * 128 + ((s ^ (ra & 7)) << 4));
  };
  auto rdB = [&](int buf, int ni, int kk) -> short8 {
    const int rb = wc * 64 + ni * 16 + (lane & 15);
    const int s  = kk * 4 + (lane >> 4);
    return *(const short8*)((const char*)&Bsm[buf][0] + rb * 128 + ((s ^ (rb & 7)) << 4));
  };

  stageA(0, 0); stageB(0, 0);
  asm volatile("s_waitcnt vmcnt(0)" ::: "memory");
  __builtin_amdgcn_s_barrier();

  int cur = 0;
#pragma unroll 1
  for (int t = 0; t < NT; ++t) {
    short8 av[4], bv[4];
    // phase 0: kk=0, mi 0..3 (+ stage A of t+1)
#pragma unroll
    for (int mi = 0; mi < 4; ++mi) av[mi] = rdA(cur, mi, 0);
#pragma unroll
    for (int ni = 0; ni < 4; ++ni) bv[ni] = rdB(cur, ni, 0);
    if (t + 1 < NT) stageA(cur ^ 1, t + 1);
    __builtin_amdgcn_s_barrier();
    asm volatile("s_waitcnt lgkmcnt(0)" ::: "memory");
    __builtin_amdgcn_sched_barrier(0);
    __builtin_amdgcn_s_setprio(1);
#pragma unroll
    for (int mi = 0; mi < 4; ++mi)
#pragma unroll
      for (int ni = 0; ni < 4; ++ni)
        acc[mi][ni] = __builtin_amdgcn_mfma_f32_16x16x32_bf16(av[mi], bv[ni], acc[mi][ni], 0, 0, 0);
    __builtin_amdgcn_s_setprio(0);
    __builtin_amdgcn_s_barrier();
    // phase 1: kk=0, mi 4..7 (+ stage B of t+1)
#pragma unroll
    for (int mi = 0; mi < 4; ++mi) av[mi] = rdA(cur, 4 + mi, 0);
    if (t + 1 < NT) stageB(cur ^ 1, t + 1);
    __builtin_amdgcn_s_barrier();
    asm volatile("s_waitcnt lgkmcnt(0)" ::: "memory");
    __builtin_amdgcn_sched_barrier(0);
    __builtin_amdgcn_s_setprio(1);
#pragma unroll
    for (int mi = 0; mi < 4; ++mi)
#pragma unroll
      for (int ni = 0; ni < 4; ++ni)
        acc[4 + mi][ni] = __builtin_amdgcn_mfma_f32_16x16x32_bf16(av[mi], bv[ni], acc[4 + mi][ni], 0, 0, 0);
    __builtin_amdgcn_s_setprio(0);
    __builtin_amdgcn_s_barrier();
    // phase 2: kk=1, mi 0..3
#pragma unroll
    for (int mi = 0; mi < 4; ++mi) av[mi] = rdA(cur, mi, 1);
#pragma unroll
    for (int ni = 0; ni < 4; ++ni) bv[ni] = rdB(cur, ni, 1);
    __builtin_amdgcn_s_barrier();
    asm volatile("s_waitcnt lgkmcnt(0)" ::: "memory");
    __builtin_amdgcn_sched_barrier(0);
    __builtin_amdgcn_s_setprio(1);
#pragma unroll
    for (int mi = 0; mi < 4; ++mi)
#pragma unroll
      for (int ni = 0; ni < 4; ++ni)
        acc[mi][ni] = __builtin_amdgcn_mfma_f32_16x16x32_bf16(av[mi], bv[ni], acc[mi][ni], 0, 0, 0);
    __builtin_amdgcn_s_setprio(0);
    __builtin_amdgcn_s_barrier();
    // phase 3: kk=1, mi 4..7 (+ vmcnt drain for t+1)
#pragma unroll
    for (int mi = 0; mi < 4; ++mi) av[mi] = rdA(cur, 4 + mi, 1);
    __builtin_amdgcn_s_barrier();
    asm volatile("s_waitcnt lgkmcnt(0)" ::: "memory");
    __builtin_amdgcn_sched_barrier(0);
    __builtin_amdgcn_s_setprio(1);
#pragma unroll
    for (int mi = 0; mi < 4; ++mi)
#pragma unroll
      for (int ni = 0; ni < 4; ++ni)
        acc[4 + mi][ni] = __builtin_amdgcn_mfma_f32_16x16x32_bf16(av[mi], bv[ni], acc[4 + mi][ni], 0, 0, 0);
    __builtin_amdgcn_s_setprio(0);
    asm volatile("s_waitcnt vmcnt(0)" ::: "memory");
    __builtin_amdgcn_s_barrier();
    cur ^= 1;
  }

  const int lc = lane & 15, lr = lane >> 4;
  if constexpr (COMBINE) {
#pragma unroll
    for (int mi = 0; mi < 8; ++mi) {
#pragma unroll
      for (int r = 0; r < 4; ++r) {
        const int row = row0 + wr * 128 + mi * 16 + lr * 4 + r;
        const int4 id = idx3[row];
        const float4 w = w3[row];
        const ushort* Yb = Ybf + (size_t)(row >> 12) * 524288;
        const ushort* y0 = Yb + (size_t)id.x * 512;
        const ushort* y1 = Yb + (size_t)id.y * 512;
        const ushort* y2 = Yb + (size_t)id.z * 512;
#pragma unroll
        for (int ni = 0; ni < 4; ++ni) {
          const int col = col0 + wc * 64 + ni * 16 + lc;
          float v = acc[mi][ni][r]
                  + w.x * bf2f(y0[col])
                  + w.y * bf2f(y1[col])
                  + w.z * bf2f(y2[col])
                  + bias[col];
          v = v > 0.f ? v : 0.f;
          ((ushort*)Cout)[(size_t)row * 512 + col] = f2bf(v);
        }
      }
    }
  } else {
#pragma unroll
    for (int mi = 0; mi < 8; ++mi) {
#pragma unroll
      for (int ni = 0; ni < 4; ++ni) {
        const int col = col0 + wc * 64 + ni * 16 + lc;
        float bv2 = 0.f;
        if constexpr (ACT) bv2 = bias[col];
        const int rbase = row0 + wr * 128 + mi * 16 + lr * 4;
#pragma unroll
        for (int r = 0; r < 4; ++r) {
          float v = acc[mi][ni][r];
          if constexpr (ACT) { v += bv2; v = v > 0.f ? v : 0.f; }
          if (OUT_BF16) ((ushort*)Cout)[(size_t)(rbase + r) * N + col] = f2bf(v);
          else          ((float*)Cout)[(size_t)(rbase + r) * N + col] = v;
        }
      }
    }
  }
}

// ---------------------------------------------------------------------------
extern "C" void kernel_launch(void* const* d_in, const int* in_sizes, int n_in,
                              void* d_out, int out_size, void* d_ws, size_t ws_size,
                              hipStream_t stream) {
  const float* x        = (const float*)d_in[0];   // [16384, 512]
  const float* pos      = (const float*)d_in[1];   // [16384, 3]
  const float* x_skip   = (const float*)d_in[3];   // [65536, 256]
  const float* pos_skip = (const float*)d_in[4];   // [65536, 3]
  const float* W1       = (const float*)d_in[6];   // [768, 512]
  const float* b1       = (const float*)d_in[7];   // [512]
  const float* W2       = (const float*)d_in[8];   // [512, 512]
  const float* b2       = (const float*)d_in[9];   // [512]

  // d_out (134,217,728 B) as scratch — all consumed before GEMM2 overwrites:
  ushort* Ybf  = (ushort*)d_out;                        // [16384][512]  16.8 MB
  ushort* xbf  = (ushort*)((char*)d_out + 83886080);    // [16384][512]  16.8 MB
  ushort* xsbf = (ushort*)((char*)d_out + 100663296);   // [65536][256]  33.5 MB

  char* ws = (char*)d_ws;
  ushort* h2   = (ushort*)ws;                          // [65536][512] bf16, 67108864 B
  ushort* W1at = (ushort*)(ws + 67108864);             // [512][512] bf16, 524288 B
  ushort* W1bt = (ushort*)(ws + 67633152);             // [512][256] bf16, 262144 B
  ushort* W2t  = (ushort*)(ws + 67895296);             // [512][512] bf16, 524288 B
  int4*   idx3 = (int4*)  (ws + 68419584);             // [65536] int4, 1 MB
  float4* w3   = (float4*)(ws + 69468160);             // [65536] float4, 1 MB

  // KNN (blocks 0..255, broadcast-scan) overlapped with all f32->bf16 converts
  prep_kernel<<<8960, 256, 0, stream>>>(pos, pos_skip, x, x_skip, W1, W2,
                                        idx3, w3, xbf, xsbf, W1at, W1bt, W2t);
  // Y = x @ W1[:512]  (coarse rows only: 16384 x 512, K=512)
  gemm_bias_relu<512, true, false, false><<<128, 512, 0, stream>>>(
      xbf, W1at, nullptr, (void*)Ybf, 16384, 512, nullptr, nullptr, nullptr);
  // h2 = relu(x_skip @ W1[512:768] + gather3(Y) + b1)   [S never materialized]
  gemm_bias_relu<256, true, false, true><<<512, 512, 0, stream>>>(
      xsbf, W1bt, b1, (void*)h2, 65536, 512, Ybf, idx3, w3);
  // out = relu(h2 @ W2 + b2), f32
  gemm_bias_relu<512, false, true, false><<<512, 512, 0, stream>>>(
      h2, W2t, b2, d_out, 65536, 512, nullptr, nullptr, nullptr);
}

// Round 20
// 168.666 us; speedup vs baseline: 1.0521x; 1.0521x over previous
//
#include <hip/hip_runtime.h>
#include <stdint.h>

typedef __attribute__((ext_vector_type(8))) short short8;
typedef __attribute__((ext_vector_type(4))) float f32x4;

static __device__ __forceinline__ ushort f2bf(float f) {
  uint32_t u = __float_as_uint(f);
  uint32_t r = (u + 0x7FFFu + ((u >> 16) & 1u)) >> 16;
  return (ushort)r;
}
static __device__ __forceinline__ float bf2f(ushort h) {
  return __uint_as_float(((uint32_t)h) << 16);
}

// Branchless top-3 insert, f64 (used only in the 4-candidate refine).
static __device__ __forceinline__ void ins3b(double d, int i,
    double& b0, double& b1, double& b2, int& i0, int& i1, int& i2) {
  const bool c0 = d < b0, c1 = d < b1, c2 = d < b2;
  const double nb0 = c0 ? d : b0;
  const int    ni0 = c0 ? i : i0;
  const double nb1 = c0 ? b0 : (c1 ? d : b1);
  const int    ni1 = c0 ? i0 : (c1 ? i : i1);
  const double nb2 = c1 ? b1 : (c2 ? d : b2);
  const int    ni2 = c1 ? i1 : (c2 ? i : i2);
  b0 = nb0; b1 = nb1; b2 = nb2; i0 = ni0; i1 = ni1; i2 = ni2;
}

// ---------------------------------------------------------------------------
// prep: blocks 0..1023 = KNN (packed-key u32 top-4 + f64 refine, 4 thr/point);
//       1024..3071 = x f32->bf16; 3072..7167 = x_skip f32->bf16;
//       7168..9727 = weight converts.
// ---------------------------------------------------------------------------
__global__ __launch_bounds__(256) void prep_kernel(
    const float* __restrict__ pos, const float* __restrict__ pos_skip,
    const float* __restrict__ x, const float* __restrict__ xs,
    const float* __restrict__ W1, const float* __restrict__ W2,
    int4* __restrict__ idx_out, float4* __restrict__ w_out,
    ushort* __restrict__ xbf, ushort* __restrict__ xsbf,
    ushort* __restrict__ W1at, ushort* __restrict__ W1bt,
    ushort* __restrict__ W2t)
{
  __shared__ float pc4[4096];          // [1024][4] padded coarse positions
  if (blockIdx.x < 1024) {
    const int b   = blockIdx.x >> 6;      // 64 blocks per batch
    const int blk = blockIdx.x & 63;      // 64 fine points per block
    for (int i = threadIdx.x; i < 1024; i += 256) {
      const float* ps = pos + (size_t)b * 3072 + i * 3;
      float4 v = { ps[0], ps[1], ps[2], 0.f };
      *(float4*)&pc4[i * 4] = v;
    }
    __syncthreads();

    const int p   = threadIdx.x >> 2;
    const int sub = threadIdx.x & 3;
    const int row = b * 4096 + blk * 64 + p;
    const float pxf = pos_skip[(size_t)row * 3 + 0];
    const float pyf = pos_skip[(size_t)row * 3 + 1];
    const float pzf = pos_skip[(size_t)row * 3 + 2];

    uint32_t c0 = 0xFFFFFFFFu, c1 = 0xFFFFFFFFu, c2 = 0xFFFFFFFFu, c3 = 0xFFFFFFFFu;
    auto ins4u = [&](uint32_t k) {
      const bool l0 = k < c0, l1 = k < c1, l2 = k < c2, l3 = k < c3;
      const uint32_t n0 = l0 ? k  : c0;
      const uint32_t n1 = l0 ? c0 : (l1 ? k : c1);
      const uint32_t n2 = l1 ? c1 : (l2 ? k : c2);
      const uint32_t n3 = l2 ? c2 : (l3 ? k : c3);
      c0 = n0; c1 = n1; c2 = n2; c3 = n3;
    };
#pragma unroll 4
    for (int j = 0; j < 256; ++j) {
      const int i = j * 4 + sub;
      const float4 q = *(const float4*)&pc4[i * 4];
      const float dx = q.x - pxf;
      const float dy = q.y - pyf;
      const float dz = q.z - pzf;
      const float d = fmaf(dx, dx, fmaf(dy, dy, dz * dz));
      ins4u((__float_as_uint(d) & 0xFFFFFC00u) | (uint32_t)i);
    }
#pragma unroll
    for (int m = 1; m <= 2; m <<= 1) {
      const uint32_t e0 = (uint32_t)__shfl_xor((int)c0, m);
      const uint32_t e1 = (uint32_t)__shfl_xor((int)c1, m);
      const uint32_t e2 = (uint32_t)__shfl_xor((int)c2, m);
      const uint32_t e3 = (uint32_t)__shfl_xor((int)c3, m);
      ins4u(e0); ins4u(e1); ins4u(e2); ins4u(e3);
    }
    if (sub == 0) {
      const double pxd = (double)pxf, pyd = (double)pyf, pzd = (double)pzf;
      auto exd = [&](int i) -> double {
        const double dx = (double)pc4[i * 4 + 0] - pxd;
        const double dy = (double)pc4[i * 4 + 1] - pyd;
        const double dz = (double)pc4[i * 4 + 2] - pzd;
        return dx * dx + dy * dy + dz * dz;
      };
      const int j0 = (int)(c0 & 1023u), j1 = (int)(c1 & 1023u);
      const int j2 = (int)(c2 & 1023u), j3 = (int)(c3 & 1023u);
      double b0 = 1e300, b1 = 1e300, b2 = 1e300;
      int i0 = 0, i1 = 0, i2 = 0;
      ins3b(exd(j0), j0, b0, b1, b2, i0, i1, i2);
      ins3b(exd(j1), j1, b0, b1, b2, i0, i1, i2);
      ins3b(exd(j2), j2, b0, b1, b2, i0, i1, i2);
      ins3b(exd(j3), j3, b0, b1, b2, i0, i1, i2);
      const double w0 = 1.0 / (sqrt(b0) + 1e-8);
      const double w1 = 1.0 / (sqrt(b1) + 1e-8);
      const double w2 = 1.0 / (sqrt(b2) + 1e-8);
      const double den = w0 + w1 + w2 + 1e-8;
      idx_out[row] = make_int4(i0, i1, i2, 0);
      w_out[row] = make_float4((float)(w0 / den), (float)(w1 / den), (float)(w2 / den), 0.f);
    }
  } else if (blockIdx.x < 3072) {
    const int id = (blockIdx.x - 1024) * 256 + threadIdx.x;   // x: 2,097,152 f4
#pragma unroll
    for (int it = 0; it < 4; ++it) {
      const int i = id + it * 524288;
      const float4 v = *(const float4*)(x + (size_t)i * 4);
      ushort4 o = { f2bf(v.x), f2bf(v.y), f2bf(v.z), f2bf(v.w) };
      *(ushort4*)(xbf + (size_t)i * 4) = o;
    }
  } else if (blockIdx.x < 7168) {
    const int id = (blockIdx.x - 3072) * 256 + threadIdx.x;   // xs: 4,194,304 f4
#pragma unroll
    for (int it = 0; it < 4; ++it) {
      const int i = id + it * 1048576;
      const float4 v = *(const float4*)(xs + (size_t)i * 4);
      ushort4 o = { f2bf(v.x), f2bf(v.y), f2bf(v.z), f2bf(v.w) };
      *(ushort4*)(xsbf + (size_t)i * 4) = o;
    }
  } else {
    const int id = (blockIdx.x - 7168) * 256 + threadIdx.x;
    if (id < 262144) {                       // W1at[n][k] = W1[k][n], k<512
      const int n = id >> 9, k = id & 511;
      W1at[id] = f2bf(W1[(size_t)k * 512 + n]);
    } else if (id < 393216) {                // W1bt[n][k] = W1[512+k][n], k<256
      const int id2 = id - 262144;
      const int n = id2 >> 8, k = id2 & 255;
      W1bt[id2] = f2bf(W1[(size_t)(512 + k) * 512 + n]);
    } else if (id < 655360) {                // W2t[n][k] = W2[k][n]
      const int id3 = id - 393216;
      const int n = id3 >> 9, k = id3 & 511;
      W2t[id3] = f2bf(W2[(size_t)k * 512 + n]);
    }
  }
}

// ---------------------------------------------------------------------------
// 256x256 8-phase bf16 MFMA GEMM (T1..T5).
// COMBINE epilogue (S-GEMM): h2 = relu(acc + gather3(Y) + b1) -> bf16,
// eliminating the S round trip entirely. acc is the f32 x_skip@W1b partial.
// ---------------------------------------------------------------------------
template<int K, bool OUT_BF16, bool ACT, bool COMBINE>
__global__ __launch_bounds__(512, 2) void gemm_bias_relu(
    const ushort* __restrict__ A, const ushort* __restrict__ Bt,
    const float* __restrict__ bias, void* __restrict__ Cout, int M, int N,
    const ushort* __restrict__ Ybf, const int4* __restrict__ idx3,
    const float4* __restrict__ w3)
{
  constexpr int BM = 256, BN = 256, BK = 64, NT = K / BK;
  __shared__ ushort Asm[2][BM * BK];   // 2 x 32 KB
  __shared__ ushort Bsm[2][BN * BK];   // 2 x 32 KB
  const int tid  = threadIdx.x;
  const int lane = tid & 63;
  const int wave = tid >> 6;

  const int cpx  = gridDim.x >> 3;
  const int wgid = (blockIdx.x & 7) * cpx + (blockIdx.x >> 3);
  const int nbn  = N / BN;
  const int bm   = wgid / nbn;
  const int bn   = wgid - bm * nbn;
  const int row0 = bm * BM, col0 = bn * BN;
  const int wr = wave >> 2, wc = wave & 3;
  const int sbase = wave * 4096 + lane * 16;

  f32x4 acc[8][4] = {};

  auto stageA = [&](int buf, int kt) {
#pragma unroll
    for (int i = 0; i < 4; ++i) {
      const int o = sbase + i * 1024;
      const int r = o >> 7, s = (o & 127) >> 4;
      __builtin_amdgcn_global_load_lds(
          (const __attribute__((address_space(1))) void*)(A + (size_t)(row0 + r) * K + kt * BK + ((s ^ (r & 7)) << 3)),
          (__attribute__((address_space(3))) void*)((char*)&Asm[buf][0] + o), 16, 0, 0);
    }
  };
  auto stageB = [&](int buf, int kt) {
#pragma unroll
    for (int i = 0; i < 4; ++i) {
      const int o = sbase + i * 1024;
      const int r = o >> 7, s = (o & 127) >> 4;
      __builtin_amdgcn_global_load_lds(
          (const __attribute__((address_space(1))) void*)(Bt + (size_t)(col0 + r) * K + kt * BK + ((s ^ (r & 7)) << 3)),
          (__attribute__((address_space(3))) void*)((char*)&Bsm[buf][0] + o), 16, 0, 0);
    }
  };
  auto rdA = [&](int buf, int mi, int kk) -> short8 {
    const int ra = wr * 128 + mi * 16 + (lane & 15);
    const int s  = kk * 4 + (lane >> 4);
    return *(const short8*)((const char*)&Asm[buf][0] + ra * 128 + ((s ^ (ra & 7)) << 4));
  };
  auto rdB = [&](int buf, int ni, int kk) -> short8 {
    const int rb = wc * 64 + ni * 16 + (lane & 15);
    const int s  = kk * 4 + (lane >> 4);
    return *(const short8*)((const char*)&Bsm[buf][0] + rb * 128 + ((s ^ (rb & 7)) << 4));
  };

  stageA(0, 0); stageB(0, 0);
  asm volatile("s_waitcnt vmcnt(0)" ::: "memory");
  __builtin_amdgcn_s_barrier();

  int cur = 0;
#pragma unroll 1
  for (int t = 0; t < NT; ++t) {
    short8 av[4], bv[4];
    // phase 0: kk=0, mi 0..3 (+ stage A of t+1)
#pragma unroll
    for (int mi = 0; mi < 4; ++mi) av[mi] = rdA(cur, mi, 0);
#pragma unroll
    for (int ni = 0; ni < 4; ++ni) bv[ni] = rdB(cur, ni, 0);
    if (t + 1 < NT) stageA(cur ^ 1, t + 1);
    __builtin_amdgcn_s_barrier();
    asm volatile("s_waitcnt lgkmcnt(0)" ::: "memory");
    __builtin_amdgcn_sched_barrier(0);
    __builtin_amdgcn_s_setprio(1);
#pragma unroll
    for (int mi = 0; mi < 4; ++mi)
#pragma unroll
      for (int ni = 0; ni < 4; ++ni)
        acc[mi][ni] = __builtin_amdgcn_mfma_f32_16x16x32_bf16(av[mi], bv[ni], acc[mi][ni], 0, 0, 0);
    __builtin_amdgcn_s_setprio(0);
    __builtin_amdgcn_s_barrier();
    // phase 1: kk=0, mi 4..7 (+ stage B of t+1)
#pragma unroll
    for (int mi = 0; mi < 4; ++mi) av[mi] = rdA(cur, 4 + mi, 0);
    if (t + 1 < NT) stageB(cur ^ 1, t + 1);
    __builtin_amdgcn_s_barrier();
    asm volatile("s_waitcnt lgkmcnt(0)" ::: "memory");
    __builtin_amdgcn_sched_barrier(0);
    __builtin_amdgcn_s_setprio(1);
#pragma unroll
    for (int mi = 0; mi < 4; ++mi)
#pragma unroll
      for (int ni = 0; ni < 4; ++ni)
        acc[4 + mi][ni] = __builtin_amdgcn_mfma_f32_16x16x32_bf16(av[mi], bv[ni], acc[4 + mi][ni], 0, 0, 0);
    __builtin_amdgcn_s_setprio(0);
    __builtin_amdgcn_s_barrier();
    // phase 2: kk=1, mi 0..3
#pragma unroll
    for (int mi = 0; mi < 4; ++mi) av[mi] = rdA(cur, mi, 1);
#pragma unroll
    for (int ni = 0; ni < 4; ++ni) bv[ni] = rdB(cur, ni, 1);
    __builtin_amdgcn_s_barrier();
    asm volatile("s_waitcnt lgkmcnt(0)" ::: "memory");
    __builtin_amdgcn_sched_barrier(0);
    __builtin_amdgcn_s_setprio(1);
#pragma unroll
    for (int mi = 0; mi < 4; ++mi)
#pragma unroll
      for (int ni = 0; ni < 4; ++ni)
        acc[mi][ni] = __builtin_amdgcn_mfma_f32_16x16x32_bf16(av[mi], bv[ni], acc[mi][ni], 0, 0, 0);
    __builtin_amdgcn_s_setprio(0);
    __builtin_amdgcn_s_barrier();
    // phase 3: kk=1, mi 4..7 (+ vmcnt drain for t+1)
#pragma unroll
    for (int mi = 0; mi < 4; ++mi) av[mi] = rdA(cur, 4 + mi, 1);
    __builtin_amdgcn_s_barrier();
    asm volatile("s_waitcnt lgkmcnt(0)" ::: "memory");
    __builtin_amdgcn_sched_barrier(0);
    __builtin_amdgcn_s_setprio(1);
#pragma unroll
    for (int mi = 0; mi < 4; ++mi)
#pragma unroll
      for (int ni = 0; ni < 4; ++ni)
        acc[4 + mi][ni] = __builtin_amdgcn_mfma_f32_16x16x32_bf16(av[mi], bv[ni], acc[4 + mi][ni], 0, 0, 0);
    __builtin_amdgcn_s_setprio(0);
    asm volatile("s_waitcnt vmcnt(0)" ::: "memory");
    __builtin_amdgcn_s_barrier();
    cur ^= 1;
  }

  const int lc = lane & 15, lr = lane >> 4;
  if constexpr (COMBINE) {
#pragma unroll
    for (int mi = 0; mi < 8; ++mi) {
#pragma unroll
      for (int r = 0; r < 4; ++r) {
        const int row = row0 + wr * 128 + mi * 16 + lr * 4 + r;
        const int4 id = idx3[row];
        const float4 w = w3[row];
        const ushort* Yb = Ybf + (size_t)(row >> 12) * 524288;
        const ushort* y0 = Yb + (size_t)id.x * 512;
        const ushort* y1 = Yb + (size_t)id.y * 512;
        const ushort* y2 = Yb + (size_t)id.z * 512;
#pragma unroll
        for (int ni = 0; ni < 4; ++ni) {
          const int col = col0 + wc * 64 + ni * 16 + lc;
          float v = acc[mi][ni][r]
                  + w.x * bf2f(y0[col])
                  + w.y * bf2f(y1[col])
                  + w.z * bf2f(y2[col])
                  + bias[col];
          v = v > 0.f ? v : 0.f;
          ((ushort*)Cout)[(size_t)row * 512 + col] = f2bf(v);
        }
      }
    }
  } else {
#pragma unroll
    for (int mi = 0; mi < 8; ++mi) {
#pragma unroll
      for (int ni = 0; ni < 4; ++ni) {
        const int col = col0 + wc * 64 + ni * 16 + lc;
        float bv2 = 0.f;
        if constexpr (ACT) bv2 = bias[col];
        const int rbase = row0 + wr * 128 + mi * 16 + lr * 4;
#pragma unroll
        for (int r = 0; r < 4; ++r) {
          float v = acc[mi][ni][r];
          if constexpr (ACT) { v += bv2; v = v > 0.f ? v : 0.f; }
          if (OUT_BF16) ((ushort*)Cout)[(size_t)(rbase + r) * N + col] = f2bf(v);
          else          ((float*)Cout)[(size_t)(rbase + r) * N + col] = v;
        }
      }
    }
  }
}

// ---------------------------------------------------------------------------
extern "C" void kernel_launch(void* const* d_in, const int* in_sizes, int n_in,
                              void* d_out, int out_size, void* d_ws, size_t ws_size,
                              hipStream_t stream) {
  const float* x        = (const float*)d_in[0];   // [16384, 512]
  const float* pos      = (const float*)d_in[1];   // [16384, 3]
  const float* x_skip   = (const float*)d_in[3];   // [65536, 256]
  const float* pos_skip = (const float*)d_in[4];   // [65536, 3]
  const float* W1       = (const float*)d_in[6];   // [768, 512]
  const float* b1       = (const float*)d_in[7];   // [512]
  const float* W2       = (const float*)d_in[8];   // [512, 512]
  const float* b2       = (const float*)d_in[9];   // [512]

  // d_out (134,217,728 B) as scratch — all consumed before GEMM2 overwrites:
  ushort* Ybf  = (ushort*)d_out;                        // [16384][512]  16.8 MB
  ushort* xbf  = (ushort*)((char*)d_out + 83886080);    // [16384][512]  16.8 MB
  ushort* xsbf = (ushort*)((char*)d_out + 100663296);   // [65536][256]  33.5 MB

  char* ws = (char*)d_ws;
  ushort* h2   = (ushort*)ws;                          // [65536][512] bf16, 67108864 B
  ushort* W1at = (ushort*)(ws + 67108864);             // [512][512] bf16, 524288 B
  ushort* W1bt = (ushort*)(ws + 67633152);             // [512][256] bf16, 262144 B
  ushort* W2t  = (ushort*)(ws + 67895296);             // [512][512] bf16, 524288 B
  int4*   idx3 = (int4*)  (ws + 68419584);             // [65536] int4, 1 MB
  float4* w3   = (float4*)(ws + 69468160);             // [65536] float4, 1 MB

  // KNN (blocks 0..1023) overlapped with all f32->bf16 converts
  prep_kernel<<<9728, 256, 0, stream>>>(pos, pos_skip, x, x_skip, W1, W2,
                                        idx3, w3, xbf, xsbf, W1at, W1bt, W2t);
  // Y = x @ W1[:512]  (coarse rows only: 16384 x 512, K=512)
  gemm_bias_relu<512, true, false, false><<<128, 512, 0, stream>>>(
      xbf, W1at, nullptr, (void*)Ybf, 16384, 512, nullptr, nullptr, nullptr);
  // h2 = relu(x_skip @ W1[512:768] + gather3(Y) + b1)   [S never materialized]
  gemm_bias_relu<256, true, false, true><<<512, 512, 0, stream>>>(
      xsbf, W1bt, b1, (void*)h2, 65536, 512, Ybf, idx3, w3);
  // out = relu(h2 @ W2 + b2), f32
  gemm_bias_relu<512, false, true, false><<<512, 512, 0, stream>>>(
      h2, W2t, b2, d_out, 65536, 512, nullptr, nullptr, nullptr);
}